// Round 1
// baseline (224.146 us; speedup 1.0000x reference)
//
#include <hip/hip_runtime.h>
#include <hip/hip_bf16.h>

typedef __attribute__((ext_vector_type(8))) short short8;
typedef __attribute__((ext_vector_type(4))) float f32x4;

#define MFMA16(a, b, c) __builtin_amdgcn_mfma_f32_16x16x32_bf16((a), (b), (c), 0, 0, 0)

constexpr int Bc = 2, Lc = 2048, Hc = 16, Ec = 64;
constexpr int NT = 32;        // kv rows per tile
constexpr int WAVES = 4;
constexpr int QBLK = 64;      // q rows per block
constexpr float SCALE = 0.125f;               // 1/sqrt(64)
constexpr float LOG2E = 1.4426950408889634f;
constexpr float NEGBIG = -3.0e38f;

__device__ __forceinline__ short f2bf(float f) {
  union { float f; unsigned u; } x; x.f = f;
  unsigned r = (x.u + 0x7FFFu + ((x.u >> 16) & 1u)) >> 16;
  return (short)r;
}

__device__ __forceinline__ short8 cvt8(const float* p) {
  const float4* q = reinterpret_cast<const float4*>(p);
  float4 a = q[0], b = q[1];
  short8 r;
  r[0] = f2bf(a.x); r[1] = f2bf(a.y); r[2] = f2bf(a.z); r[3] = f2bf(a.w);
  r[4] = f2bf(b.x); r[5] = f2bf(b.y); r[6] = f2bf(b.z); r[7] = f2bf(b.w);
  return r;
}

__global__ __launch_bounds__(256, 4)
void attn_fwd(const float* __restrict__ Qg, const float* __restrict__ Kg,
              const float* __restrict__ Vg, float* __restrict__ Og) {
  // K tile: row-major [32][64] bf16, XOR-swizzled byte^((row&7)<<4)  (shorts: <<3)
  // V tile: row-major [32][64] bf16, XOR-swizzled byte^(((row>>3)&3)<<4)
  __shared__ __align__(16) short kt[NT * Ec];
  __shared__ __align__(16) short vt[NT * Ec];
  __shared__ __align__(16) short pt[WAVES][16 * NT];  // per-wave P tile 16x32

  const int nqb = Lc / QBLK;                 // 32
  const int bid = blockIdx.x;
  const int qblk = (nqb - 1) - (bid % nqb);  // heavy (high-q) blocks first
  const int h = (bid / nqb) % Hc;
  const int b = bid / (nqb * Hc);
  const int Qb = qblk * QBLK;

  const int t = threadIdx.x;
  const int w = t >> 6;   // wave id: q sub-block
  const int l = t & 63;
  const int n = l & 15;
  const int g = l >> 4;

  // ---- Q fragments (A-layout: row = n, k = g*8+j), 2 k-chunks over E=64 ----
  short8 qf[2];
  {
    const int q = Qb + w * 16 + n;
    const float* qp = Qg + ((size_t)(b * Lc + q) * Hc + h) * Ec + g * 8;
    qf[0] = cvt8(qp);
    qf[1] = cvt8(qp + 32);
  }

  f32x4 acc[4] = {{0,0,0,0},{0,0,0,0},{0,0,0,0},{0,0,0,0}};
  float mrun[4] = {NEGBIG, NEGBIG, NEGBIG, NEGBIG};
  float lrun[4] = {0.f, 0.f, 0.f, 0.f};

  const int qmax_w = Qb + w * 16 + 15;
  const int nsb = (Qb + QBLK) / NT;

  for (int sb = 0; sb < nsb; ++sb) {
    const int sbase = sb * NT;

    // ---- stage K,V tile: 256 threads, 8 contiguous fp32 each per tensor ----
    {
      const int row = t >> 3;          // 0..31
      const int c8 = (t & 7) * 8;      // 0..56
      const size_t roff = ((size_t)(b * Lc + sbase + row) * Hc + h) * Ec + c8;
      short8 kv = cvt8(Kg + roff);
      short8 vv = cvt8(Vg + roff);
      const int kidx = (row * 64 + c8) ^ ((row & 7) << 3);
      *reinterpret_cast<short8*>(&kt[kidx]) = kv;
      const int vidx = (row * 64 + c8) ^ (((row >> 3) & 3) << 3);
      *reinterpret_cast<short8*>(&vt[vidx]) = vv;
    }
    __syncthreads();

    if (sbase <= qmax_w) {
      // ---- QK^T: scores[16 q][32 s] ----
      f32x4 sc[2] = {{0,0,0,0},{0,0,0,0}};
      #pragma unroll
      for (int c = 0; c < 2; ++c) {
        #pragma unroll
        for (int cb = 0; cb < 2; ++cb) {
          const int row = cb * 16 + n;   // s within tile
          const int idx = (row * 64 + c * 32 + g * 8) ^ ((row & 7) << 3);
          short8 kf = *reinterpret_cast<const short8*>(&kt[idx]);
          sc[cb] = MFMA16(qf[c], kf, sc[cb]);
        }
      }

      // ---- online softmax; C layout: row q16 = g*4+r, col s16 = n ----
      float s_f[2][4];
      const bool domask = (sbase + NT - 1) > (Qb + w * 16);
      #pragma unroll
      for (int cb = 0; cb < 2; ++cb) {
        #pragma unroll
        for (int r = 0; r < 4; ++r) {
          float v = sc[cb][r] * SCALE;
          if (domask) {
            const int s = sbase + cb * 16 + n;
            const int q = Qb + w * 16 + g * 4 + r;
            if (s > q) v = NEGBIG;
          }
          s_f[cb][r] = v;
        }
      }
      float mx[4];
      #pragma unroll
      for (int r = 0; r < 4; ++r) mx[r] = fmaxf(s_f[0][r], s_f[1][r]);
      #pragma unroll
      for (int msk = 1; msk < 16; msk <<= 1) {
        #pragma unroll
        for (int r = 0; r < 4; ++r) mx[r] = fmaxf(mx[r], __shfl_xor(mx[r], msk));
      }
      float p[2][4], rsum[4], afac[4];
      #pragma unroll
      for (int r = 0; r < 4; ++r) {
        const float mn = fmaxf(mrun[r], mx[r]);
        afac[r] = exp2f((mrun[r] - mn) * LOG2E);
        mrun[r] = mn;
        rsum[r] = 0.f;
      }
      #pragma unroll
      for (int cb = 0; cb < 2; ++cb) {
        #pragma unroll
        for (int r = 0; r < 4; ++r) {
          const float e = exp2f((s_f[cb][r] - mrun[r]) * LOG2E);
          p[cb][r] = e;
          rsum[r] += e;
        }
      }
      #pragma unroll
      for (int msk = 1; msk < 16; msk <<= 1) {
        #pragma unroll
        for (int r = 0; r < 4; ++r) rsum[r] += __shfl_xor(rsum[r], msk);
      }
      #pragma unroll
      for (int r = 0; r < 4; ++r) lrun[r] = lrun[r] * afac[r] + rsum[r];
      #pragma unroll
      for (int e4 = 0; e4 < 4; ++e4) {
        #pragma unroll
        for (int r = 0; r < 4; ++r) acc[e4][r] *= afac[r];
      }

      // ---- P: C-layout regs -> LDS -> A-layout frag ----
      #pragma unroll
      for (int cb = 0; cb < 2; ++cb) {
        #pragma unroll
        for (int r = 0; r < 4; ++r)
          pt[w][(g * 4 + r) * NT + cb * 16 + n] = f2bf(p[cb][r]);
      }
      asm volatile("s_waitcnt lgkmcnt(0)" ::: "memory");
      short8 pf = *reinterpret_cast<const short8*>(&pt[w][n * NT + g * 8]);

      // ---- PV: acc[16 q][64 e] += P[16][32] * V[32][64] ----
      #pragma unroll
      for (int e4 = 0; e4 < 4; ++e4) {
        short8 vf;
        #pragma unroll
        for (int j = 0; j < 8; ++j) {
          const int row = g * 8 + j;
          vf[j] = vt[(row * 64 + e4 * 16 + n) ^ (g << 3)];
        }
        acc[e4] = MFMA16(pf, vf, acc[e4]);
      }
    }
    __syncthreads();
  }

  // ---- epilogue: normalize and store fp32 ----
  #pragma unroll
  for (int r = 0; r < 4; ++r) {
    const float inv = 1.0f / lrun[r];
    const int q = Qb + w * 16 + g * 4 + r;
    float* op = Og + ((size_t)(b * Lc + q) * Hc + h) * Ec + n;
    #pragma unroll
    for (int e4 = 0; e4 < 4; ++e4) op[e4 * 16] = acc[e4][r] * inv;
  }
}

extern "C" void kernel_launch(void* const* d_in, const int* in_sizes, int n_in,
                              void* d_out, int out_size, void* d_ws, size_t ws_size,
                              hipStream_t stream) {
  const float* Q = (const float*)d_in[0];
  const float* K = (const float*)d_in[1];
  const float* V = (const float*)d_in[2];
  float* O = (float*)d_out;
  dim3 grid(Bc * Hc * (Lc / QBLK));
  attn_fwd<<<grid, dim3(256), 0, stream>>>(Q, K, V, O);
}

// Round 2
// 154.706 us; speedup vs baseline: 1.4488x; 1.4488x over previous
//
#include <hip/hip_runtime.h>
#include <hip/hip_bf16.h>

typedef __attribute__((ext_vector_type(8))) short short8;
typedef __attribute__((ext_vector_type(4))) float f32x4;

#define MFMA16(a, b, c) __builtin_amdgcn_mfma_f32_16x16x32_bf16((a), (b), (c), 0, 0, 0)

constexpr int Bc = 2, Lc = 2048, Hc = 16, Ec = 64;
constexpr int NT = 32;        // kv rows per tile
constexpr int WAVES = 4;
constexpr int QBLK = 64;      // q rows per block
constexpr float SCALE = 0.125f;               // 1/sqrt(64), exact in bf16
constexpr float LOG2E = 1.4426950408889634f;
constexpr float NEGBIG = -3.0e38f;

__device__ __forceinline__ short f2bf(float f) {
  union { float f; unsigned u; } x; x.f = f;
  return (short)((x.u + 0x7FFFu + ((x.u >> 16) & 1u)) >> 16);
}

// 16-lane max reduction step on the VALU pipe (DPP), not LDS.
template <int CTRL>
__device__ __forceinline__ float dppmax(float x) {
  int xi = __builtin_bit_cast(int, x);
  int yi = __builtin_amdgcn_update_dpp(xi, xi, CTRL, 0xF, 0xF, false);
  return fmaxf(x, __builtin_bit_cast(float, yi));
}

__global__ __launch_bounds__(256, 2)
void attn_fwd(const float* __restrict__ Qg, const float* __restrict__ Kg,
              const float* __restrict__ Vg, float* __restrict__ Og) {
  // K tile: row-major [32][64] bf16, swizzle shorts: idx ^ ((row&7)<<3)
  // V tile: TRANSPOSED [64 e][32 s] bf16, swizzle: s>>3 field XOR ((e>>1)^(e>>3))&3
  __shared__ __align__(16) short kt[2][NT * Ec];
  __shared__ __align__(16) short vt[2][Ec * NT];
  __shared__ __align__(16) short pt[WAVES][16 * NT];  // per-wave P tile 16x32

  const int nqb = Lc / QBLK;                 // 32
  const int bid = blockIdx.x;
  const int qblk = (nqb - 1) - (bid % nqb);  // heavy (high-q) blocks first
  const int h = (bid / nqb) % Hc;
  const int b = bid / (nqb * Hc);
  const int Qb = qblk * QBLK;

  const int t = threadIdx.x;
  const int w = t >> 6;   // wave id: q sub-block
  const int l = t & 63;
  const int n = l & 15;
  const int g = l >> 4;

  // ---- Q fragments (A-layout: row = n, k = g*8+j), scale folded in ----
  short8 qf[2];
  {
    const int q = Qb + w * 16 + n;
    const float* qp = Qg + ((size_t)(b * Lc + q) * Hc + h) * Ec + g * 8;
    #pragma unroll
    for (int j = 0; j < 8; ++j) qf[0][j] = f2bf(qp[j] * SCALE);
    #pragma unroll
    for (int j = 0; j < 8; ++j) qf[1][j] = f2bf(qp[32 + j] * SCALE);
  }

  short8 onesv;
  #pragma unroll
  for (int j = 0; j < 8; ++j) onesv[j] = (short)0x3F80;  // bf16 1.0
  const f32x4 zero4 = {0.f, 0.f, 0.f, 0.f};

  f32x4 acc[4] = {zero4, zero4, zero4, zero4};
  float mrun[4] = {NEGBIG, NEGBIG, NEGBIG, NEGBIG};
  float lrun[4] = {0.f, 0.f, 0.f, 0.f};

  // staging coordinates
  const int srow = t >> 3, sc8 = (t & 7) * 8;   // K: row 0..31, 8 cols
  const int ve = l, vs0 = w * 8;                // V^T: col e = lane, 8 s rows
  const int vxe = ((ve >> 1) ^ (ve >> 3)) & 3;

  float4 ka, kb;
  float va[8];

  auto issue = [&](int sbase) {
    const float* kp = Kg + ((size_t)(b * Lc + sbase + srow) * Hc + h) * Ec + sc8;
    ka = reinterpret_cast<const float4*>(kp)[0];
    kb = reinterpret_cast<const float4*>(kp)[1];
    const float* vp = Vg + ((size_t)(b * Lc + sbase + vs0) * Hc + h) * Ec + ve;
    #pragma unroll
    for (int j = 0; j < 8; ++j) va[j] = vp[(size_t)j * (Hc * Ec)];
  };
  auto commit = [&](int buf) {
    short8 kv;
    kv[0] = f2bf(ka.x); kv[1] = f2bf(ka.y); kv[2] = f2bf(ka.z); kv[3] = f2bf(ka.w);
    kv[4] = f2bf(kb.x); kv[5] = f2bf(kb.y); kv[6] = f2bf(kb.z); kv[7] = f2bf(kb.w);
    *reinterpret_cast<short8*>(&kt[buf][(srow * 64 + sc8) ^ ((srow & 7) << 3)]) = kv;
    short8 vv;
    #pragma unroll
    for (int j = 0; j < 8; ++j) vv[j] = f2bf(va[j]);
    *reinterpret_cast<short8*>(&vt[buf][ve * 32 + ((w ^ vxe) << 3)]) = vv;
  };

  const int qmax_w = Qb + w * 16 + 15;
  const int nsb = (Qb + QBLK) / NT;

  issue(0);
  commit(0);
  __syncthreads();

  int cur = 0;
  for (int sb = 0; sb < nsb; ++sb) {
    const int sbase = sb * NT;
    const bool pre = (sb + 1 < nsb);
    if (pre) issue(sbase + NT);   // global loads overlap compute below

    if (sbase <= qmax_w) {
      // ---- QK^T: scores[16 q][32 s] ----
      f32x4 sc[2] = {zero4, zero4};
      #pragma unroll
      for (int c = 0; c < 2; ++c) {
        #pragma unroll
        for (int cb = 0; cb < 2; ++cb) {
          const int row = cb * 16 + n;   // s within tile
          const int idx = (row * 64 + c * 32 + g * 8) ^ ((row & 7) << 3);
          short8 kf = *reinterpret_cast<const short8*>(&kt[cur][idx]);
          sc[cb] = MFMA16(qf[c], kf, sc[cb]);
        }
      }

      // ---- online softmax; C layout: row q16 = g*4+r, col s16 = n ----
      float s_f[2][4];
      const bool domask = (sbase + NT - 1) > (Qb + w * 16);
      #pragma unroll
      for (int cb = 0; cb < 2; ++cb) {
        #pragma unroll
        for (int r = 0; r < 4; ++r) {
          float v = sc[cb][r];
          if (domask) {
            const int s = sbase + cb * 16 + n;
            const int q = Qb + w * 16 + g * 4 + r;
            if (s > q) v = NEGBIG;
          }
          s_f[cb][r] = v;
        }
      }
      // row max over the 16 n-lanes: 4 DPP steps, VALU pipe
      float mx[4];
      #pragma unroll
      for (int r = 0; r < 4; ++r) mx[r] = fmaxf(s_f[0][r], s_f[1][r]);
      #pragma unroll
      for (int r = 0; r < 4; ++r) mx[r] = dppmax<0xB1>(mx[r]);   // xor1
      #pragma unroll
      for (int r = 0; r < 4; ++r) mx[r] = dppmax<0x4E>(mx[r]);   // xor2
      #pragma unroll
      for (int r = 0; r < 4; ++r) mx[r] = dppmax<0x141>(mx[r]);  // half mirror
      #pragma unroll
      for (int r = 0; r < 4; ++r) mx[r] = dppmax<0x140>(mx[r]);  // mirror

      float afac[4];
      #pragma unroll
      for (int r = 0; r < 4; ++r) {
        const float mn = fmaxf(mrun[r], mx[r]);
        afac[r] = exp2f((mrun[r] - mn) * LOG2E);
        mrun[r] = mn;
      }

      // ---- P -> bf16 -> LDS (C layout) -> A-layout frag ----
      #pragma unroll
      for (int cb = 0; cb < 2; ++cb) {
        #pragma unroll
        for (int r = 0; r < 4; ++r) {
          const float e = exp2f((s_f[cb][r] - mrun[r]) * LOG2E);
          pt[w][(g * 4 + r) * NT + cb * 16 + n] = f2bf(e);
        }
      }
      asm volatile("s_waitcnt lgkmcnt(0)" ::: "memory");
      short8 pf = *reinterpret_cast<const short8*>(&pt[w][n * NT + g * 8]);

      // row sums via ones-MFMA: C row g*4+r lines up with lrun[r]
      f32x4 rs = MFMA16(pf, onesv, zero4);
      #pragma unroll
      for (int r = 0; r < 4; ++r) lrun[r] = lrun[r] * afac[r] + rs[r];
      #pragma unroll
      for (int e4 = 0; e4 < 4; ++e4) {
        #pragma unroll
        for (int r = 0; r < 4; ++r) acc[e4][r] *= afac[r];
      }

      // ---- PV: B-frag = contiguous ds_read_b128 from V^T ----
      #pragma unroll
      for (int e4 = 0; e4 < 4; ++e4) {
        const int e = e4 * 16 + n;
        const int xe = ((e >> 1) ^ (e >> 3)) & 3;
        short8 vf = *reinterpret_cast<const short8*>(&vt[cur][e * 32 + ((g ^ xe) << 3)]);
        acc[e4] = MFMA16(pf, vf, acc[e4]);
      }
    }

    if (pre) commit(cur ^ 1);   // convert + LDS write after compute
    __syncthreads();
    cur ^= 1;
  }

  // ---- epilogue: normalize and store fp32 ----
  #pragma unroll
  for (int r = 0; r < 4; ++r) {
    const float inv = 1.0f / lrun[r];
    const int q = Qb + w * 16 + g * 4 + r;
    float* op = Og + ((size_t)(b * Lc + q) * Hc + h) * Ec + n;
    #pragma unroll
    for (int e4 = 0; e4 < 4; ++e4) op[e4 * 16] = acc[e4][r] * inv;
  }
}

extern "C" void kernel_launch(void* const* d_in, const int* in_sizes, int n_in,
                              void* d_out, int out_size, void* d_ws, size_t ws_size,
                              hipStream_t stream) {
  const float* Q = (const float*)d_in[0];
  const float* K = (const float*)d_in[1];
  const float* V = (const float*)d_in[2];
  float* O = (float*)d_out;
  dim3 grid(Bc * Hc * (Lc / QBLK));
  attn_fwd<<<grid, dim3(256), 0, stream>>>(Q, K, V, O);
}